// Round 9
// baseline (1324.235 us; speedup 1.0000x reference)
//
#include <hip/hip_runtime.h>
#include <hip/hip_bf16.h>
#include <stdint.h>

#define BB 16
#define NN 4096
#define NPOINT 1024
#define NSAMPLE 32

typedef unsigned int u32;
typedef unsigned long long u64;
typedef unsigned short u16;
typedef float f32x2 __attribute__((ext_vector_type(2)));
using frag_ab = __attribute__((ext_vector_type(8))) short;   // 8 bf16 (4 VGPRs)
using frag_cd = __attribute__((ext_vector_type(4))) float;   // 4 fp32

__device__ inline u16 f2bf(float x){ u32 u = __float_as_uint(x); u32 r = (u + 0x7fffu + ((u>>16)&1u)) >> 16; return (u16)r; }
__device__ inline float bf2f(u32 hbits){ return __uint_as_float(hbits<<16); }
__device__ inline u64 umax64(u64 a, u64 b){ return a > b ? a : b; }

// full-wave (64-lane) f32 max via DPP; result bits returned from lane 63.
__device__ inline int wave_max_bits(float v){
    int x = __float_as_int(v);
    int t;
    t = __builtin_amdgcn_update_dpp(0, x, 0x111, 0xf, 0xf, true);  // row_shr:1
    x = __float_as_int(fmaxf(__int_as_float(x), __int_as_float(t)));
    t = __builtin_amdgcn_update_dpp(0, x, 0x112, 0xf, 0xf, true);  // row_shr:2
    x = __float_as_int(fmaxf(__int_as_float(x), __int_as_float(t)));
    t = __builtin_amdgcn_update_dpp(0, x, 0x114, 0xf, 0xf, true);  // row_shr:4
    x = __float_as_int(fmaxf(__int_as_float(x), __int_as_float(t)));
    t = __builtin_amdgcn_update_dpp(0, x, 0x118, 0xf, 0xf, true);  // row_shr:8
    x = __float_as_int(fmaxf(__int_as_float(x), __int_as_float(t)));
    t = __builtin_amdgcn_update_dpp(0, x, 0x142, 0xf, 0xf, true);  // row_bcast:15
    x = __float_as_int(fmaxf(__int_as_float(x), __int_as_float(t)));
    t = __builtin_amdgcn_update_dpp(0, x, 0x143, 0xf, 0xf, true);  // row_bcast:31
    x = __float_as_int(fmaxf(__int_as_float(x), __int_as_float(t)));
    return __builtin_amdgcn_readlane(x, 63);
}

// ================= MEGA: blocks 0..15 = FPS (R3-exact + progress publish);
// ================= blocks 16..255 = workers (pack -> per-centroid ballquery + new_xyz + conv1)
// Co-residency: 256 blocks, each CU fits >=2 (50KB LDS, ~160 VGPR) => no deadlock possible.
// fps never waits on workers; workers wait only on unconditionally-reached events.
__global__ __launch_bounds__(256) void mega_kernel(const float* __restrict__ xyz, const float* __restrict__ points,
    const float* __restrict__ w0, const float* __restrict__ bias0,
    int* __restrict__ cents, u32* __restrict__ pbf, int* __restrict__ gidx,
    float* __restrict__ out, float* __restrict__ stats,
    int* __restrict__ progress, int* __restrict__ packdone, u32* __restrict__ x1buf)
{
#pragma clang fp contract(off)
    __shared__ float lxyz[NN*3];
    __shared__ __align__(16) u64 s_red[2][4];
    const int tid = threadIdx.x;
    const int lane = tid & 63;
    const int wid = tid >> 6;

    if (blockIdx.x < 16){
        // ---------------- FPS (R3-exact, 544us measured) ----------------
        const int b = blockIdx.x;
        const float* gx = xyz + (size_t)b*NN*3;
        for (int i = tid; i < NN*3; i += 256) lxyz[i] = gx[i];
        __syncthreads();
        f32x2 px[8], py[8], pz[8], dist[8];
#pragma unroll
        for (int jj = 0; jj < 8; jj++){
            int p = tid*16 + jj*2;
            px[jj] = (f32x2){ lxyz[p*3+0], lxyz[(p+1)*3+0] };
            py[jj] = (f32x2){ lxyz[p*3+1], lxyz[(p+1)*3+1] };
            pz[jj] = (f32x2){ lxyz[p*3+2], lxyz[(p+1)*3+2] };
            dist[jj] = (f32x2){ 1e10f, 1e10f };
        }
        int far = 0, par = 0;
        for (int s = 0; s < NPOINT; s++){
            if (tid == 0){
                cents[b*NPOINT + s] = far;
                if ((s & 15) == 15)   // release: drains prior cents stores; amortized over 16 steps
                    __hip_atomic_store(&progress[b], s + 1, __ATOMIC_RELEASE, __HIP_MEMORY_SCOPE_AGENT);
            }
            float cx = lxyz[far*3+0], cy = lxyz[far*3+1], cz = lxyz[far*3+2];
            f32x2 c2x = { cx, cx }, c2y = { cy, cy }, c2z = { cz, cz };
            float bv = -1.0f; int bj = 0;
#pragma unroll
            for (int jj = 0; jj < 8; jj++){
                f32x2 dx = px[jj] - c2x;
                f32x2 dy = py[jj] - c2y;
                f32x2 dz = pz[jj] - c2z;
                f32x2 d  = (dx*dx + dy*dy) + dz*dz;     // contract(off): exact _rn order
                f32x2 nd;
                nd.x = fminf(dist[jj].x, d.x);
                nd.y = fminf(dist[jj].y, d.y);
                dist[jj] = nd;
                if (nd.x > bv){ bv = nd.x; bj = jj*2; }       // ascending j => first-max kept
                if (nd.y > bv){ bv = nd.y; bj = jj*2+1; }
            }
            int wmb = wave_max_bits(bv);
            float wmax = __int_as_float(wmb);
            u64 mask = __ballot(bv == wmax);
            int fl = __ffsll((long long)mask) - 1;             // lowest lane => lowest p
            int fj = __builtin_amdgcn_readlane(bj, fl);
            int p = (wid << 10) + (fl << 4) + fj;
            if (lane == 0) s_red[par][wid] = ((u64)(u32)wmb << 32) | (u32)(4095 - p);
            __syncthreads();
            u64 m0 = umax64(s_red[par][0], s_red[par][1]);
            u64 m1 = umax64(s_red[par][2], s_red[par][3]);
            u64 m  = umax64(m0, m1);
            far = 4095 - (int)(m & 0xFFFu);
            par ^= 1;
        }
    } else {
        // ---------------- workers ----------------
        const int wi = blockIdx.x - 16;       // 0..239
        // phase 0: pack points to bf16 (grid-stride over 240 worker blocks)
        for (int i = wi*256 + tid; i < BB*NN*32; i += 240*256){
            float f0 = points[2*i], f1 = points[2*i+1];
            pbf[i] = (u32)f2bf(f0) | ((u32)f2bf(f1) << 16);
        }
        __syncthreads();
        if (tid == 0){ __threadfence(); atomicAdd(packdone, 1); }
        // conv1 weight fragments (independent of fps)
        const int quad = lane >> 4;
        const int col = lane & 15;
        frag_ab Bf[4][2];
#pragma unroll
        for (int nt = 0; nt < 4; nt++)
#pragma unroll
            for (int kh = 0; kh < 2; kh++){
                const float* wr = w0 + (nt*16 + col)*67 + 3 + kh*32 + quad*8;
#pragma unroll
                for (int j = 0; j < 8; j++) Bf[nt][kh][j] = (short)f2bf(wr[j]);
            }
        float wx[4], wy[4], wz[4], biasl[4];
#pragma unroll
        for (int nt = 0; nt < 4; nt++){
            const float* wb = w0 + (nt*16 + col)*67;
            wx[nt] = wb[0]; wy[nt] = wb[1]; wz[nt] = wb[2];
            biasl[nt] = bias0[nt*16 + col];
        }
        // wait for all packs (every block reaches its pack unconditionally -> no deadlock)
        while (__hip_atomic_load(packdone, __ATOMIC_ACQUIRE, __HIP_MEMORY_SCOPE_AGENT) < 240)
            __builtin_amdgcn_s_sleep(10);
        float ssum[4] = {0,0,0,0}, ssq[4] = {0,0,0,0};
        u16* xo = (u16*)x1buf;
        const float RAD2 = (float)(0.9*0.9);
        const int wwave = wi*4 + wid;          // 0..959
        for (int g = wwave; g < BB*NPOINT; g += 960){
            const int b = g >> 10, s = g & 1023;
            while (__hip_atomic_load(&progress[b], __ATOMIC_ACQUIRE, __HIP_MEMORY_SCOPE_AGENT) <= s)
                __builtin_amdgcn_s_sleep(10);
            const int ci = cents[b*NPOINT + s];
            const float* cp = xyz + ((size_t)b*NN + ci)*3;
            float cx = cp[0], cy = cp[1], cz = cp[2];
            if (lane < 3) out[g*3 + lane] = cp[lane];   // new_xyz output
            // ---- ball query (verbatim math) ----
            float sc = __fadd_rn(__fadd_rn(__fmul_rn(cx,cx), __fmul_rn(cy,cy)), __fmul_rn(cz,cz));
            const float* gx = xyz + (size_t)b*NN*3;
            int* gout = gidx + (size_t)g*NSAMPLE;
            int found = 0; int first = -1;
            for (int base = 0; base < NN; base += 64){
                int i = base + lane;
                float pxv = gx[i*3+0], pyv = gx[i*3+1], pzv = gx[i*3+2];
                float sp = __fadd_rn(__fadd_rn(__fmul_rn(pxv,pxv), __fmul_rn(pyv,pyv)), __fmul_rn(pzv,pzv));
                float dot = __fadd_rn(__fadd_rn(__fmul_rn(cx,pxv), __fmul_rn(cy,pyv)), __fmul_rn(cz,pzv));
                float d2 = __fsub_rn(__fadd_rn(sc, sp), __fmul_rn(2.0f, dot));
                float dd = __fsqrt_rn(fmaxf(d2, 0.0f));
                bool in = !(dd > RAD2);
                u64 m = __ballot(in);
                int cnt = __popcll(m);
                if (in){
                    int slot = found + __popcll(m & ((1ull<<lane) - 1ull));
                    if (slot < NSAMPLE) gout[slot] = i;
                }
                if (found == 0 && cnt > 0) first = base + (__ffsll(m) - 1);
                found += cnt;
                if (found >= NSAMPLE) break;
            }
            if (found < NSAMPLE){
                if (found == 0) first = ci;
                for (int slot = found + lane; slot < NSAMPLE; slot += 64) gout[slot] = first;
            }
            __threadfence();   // own-wave gidx stores -> visible to own-wave loads below
            // ---- conv1 for this centroid's 32 rows (2 MFMA tiles) ----
#pragma unroll
            for (int t = 0; t < 2; t++){
                const int m0 = g*32 + t*16;
                const int gg = gidx[m0 + col];
                const u32* arow = pbf + ((size_t)(b<<12) + gg)*32;
                uint4 u0 = *(const uint4*)(arow + quad*4);
                uint4 u1 = *(const uint4*)(arow + 16 + quad*4);
                frag_ab Af0, Af1;
                __builtin_memcpy(&Af0, &u0, 16);
                __builtin_memcpy(&Af1, &u1, 16);
                frag_cd acc[4];
#pragma unroll
                for (int nt = 0; nt < 4; nt++){
                    acc[nt] = (frag_cd){0.f, 0.f, 0.f, 0.f};
                    acc[nt] = __builtin_amdgcn_mfma_f32_16x16x32_bf16(Af0, Bf[nt][0], acc[nt], 0, 0, 0);
                    acc[nt] = __builtin_amdgcn_mfma_f32_16x16x32_bf16(Af1, Bf[nt][1], acc[nt], 0, 0, 0);
                }
#pragma unroll
                for (int r = 0; r < 4; r++){
                    const int rowm = m0 + quad*4 + r;
                    const int pt = gidx[rowm];
                    const float* p3 = xyz + ((size_t)(b<<12) + pt)*3;
                    float xnx = p3[0]-cx, xny = p3[1]-cy, xnz = p3[2]-cz;
#pragma unroll
                    for (int nt = 0; nt < 4; nt++){
                        float v = acc[nt][r] + biasl[nt];
                        v = fmaf(wx[nt], xnx, v);
                        v = fmaf(wy[nt], xny, v);
                        v = fmaf(wz[nt], xnz, v);
                        xo[(size_t)rowm*64 + nt*16 + col] = f2bf(v);
                        ssum[nt] += v;
                        ssq[nt] = fmaf(v, v, ssq[nt]);
                    }
                }
            }
        }
        // stats reduce (lanes sharing col) + global atomics
#pragma unroll
        for (int nt = 0; nt < 4; nt++){
            ssum[nt] += __shfl_xor(ssum[nt], 16); ssq[nt] += __shfl_xor(ssq[nt], 16);
            ssum[nt] += __shfl_xor(ssum[nt], 32); ssq[nt] += __shfl_xor(ssq[nt], 32);
        }
        if (quad == 0){
            float* st = stats + (wi & 7)*256;
#pragma unroll
            for (int nt = 0; nt < 4; nt++){
                atomicAdd(&st[nt*16 + col], ssum[nt]);
                atomicAdd(&st[128 + nt*16 + col], ssq[nt]);
            }
        }
    }
}

// ---- in-block BN finalize: stats (8 replicas) + g/beta -> saff[a:0..127 | b:128..255] ----
__device__ inline void block_finalize(const float* __restrict__ stats, const float* __restrict__ g,
                                      const float* __restrict__ beta, float* saff, int C, int tid)
{
    if (tid < C){
        float sm = 0.f, sq = 0.f;
#pragma unroll
        for (int r = 0; r < 8; r++){ sm += stats[r*256+tid]; sq += stats[r*256+128+tid]; }
        const float invM = 1.0f / 524288.0f;
        float mu  = sm * invM;
        float var = fmaxf(sq * invM - mu*mu, 0.0f);
        float inv = 1.0f / sqrtf(var + 1e-5f);
        float a = g[tid] * inv;
        saff[tid] = a;
        saff[128+tid] = beta[tid] - mu*a;
    }
}

// ---- unpack 8 packed-bf16, apply affine+relu, emit bf16 frag half ----
__device__ inline void unpack_affine_relu(uint4 u, const float* ak, const float* bk, short* dst){
    const u32* uu = (const u32*)&u;
#pragma unroll
    for (int q = 0; q < 4; q++){
        u32 v = uu[q];
        float x0 = bf2f(v & 0xffffu);
        float x1 = bf2f(v >> 16);
        float f0 = fmaxf(fmaf(ak[2*q],   x0, bk[2*q]),   0.f);
        float f1 = fmaxf(fmaf(ak[2*q+1], x1, bk[2*q+1]), 0.f);
        dst[2*q]   = (short)f2bf(f0);
        dst[2*q+1] = (short)f2bf(f1);
    }
}

// ---------------- conv2 (MFMA): 64->64, in-block BN0 finalize, BN+relu on load, fused stats ----------------
__global__ __launch_bounds__(256) void conv2_kernel(const u32* __restrict__ xin, const float* __restrict__ stats_in,
                                                    const float* __restrict__ gw, const float* __restrict__ beta,
                                                    const float* __restrict__ w, const float* __restrict__ bias,
                                                    u32* __restrict__ xout, float* __restrict__ stats)
{
    __shared__ float saff[256];
    const int tid = threadIdx.x;
    block_finalize(stats_in, gw, beta, saff, 64, tid);
    const int lane = tid & 63;
    const int wid = tid >> 6;
    const int quad = lane >> 4;
    const int col = lane & 15;
    frag_ab Bf[4][2];
#pragma unroll
    for (int nt = 0; nt < 4; nt++)
#pragma unroll
        for (int kh = 0; kh < 2; kh++){
            const float* wr = w + (nt*16 + col)*64 + kh*32 + quad*8;
#pragma unroll
            for (int j = 0; j < 8; j++) Bf[nt][kh][j] = (short)f2bf(wr[j]);
        }
    float biasl[4];
#pragma unroll
    for (int nt = 0; nt < 4; nt++) biasl[nt] = bias[nt*16 + col];
    __syncthreads();
    float ak[2][8], bk[2][8];
#pragma unroll
    for (int kh = 0; kh < 2; kh++)
#pragma unroll
        for (int j = 0; j < 8; j++){
            int k = kh*32 + quad*8 + j;
            ak[kh][j] = saff[k]; bk[kh][j] = saff[128+k];
        }
    float ssum[4] = {0,0,0,0}, ssq[4] = {0,0,0,0};
    u16* xo = (u16*)xout;
    const int tile0 = blockIdx.x*64 + wid*16;
    for (int t = 0; t < 16; t++){
        const size_t m0 = (size_t)(tile0 + t) * 16;
        const u32* arow = xin + (m0 + col)*32;
        uint4 u0 = *(const uint4*)(arow + quad*4);
        uint4 u1 = *(const uint4*)(arow + 16 + quad*4);
        frag_ab Af0, Af1;
        unpack_affine_relu(u0, ak[0], bk[0], (short*)&Af0);
        unpack_affine_relu(u1, ak[1], bk[1], (short*)&Af1);
        frag_cd acc[4];
#pragma unroll
        for (int nt = 0; nt < 4; nt++){
            acc[nt] = (frag_cd){biasl[nt], biasl[nt], biasl[nt], biasl[nt]};
            acc[nt] = __builtin_amdgcn_mfma_f32_16x16x32_bf16(Af0, Bf[nt][0], acc[nt], 0, 0, 0);
            acc[nt] = __builtin_amdgcn_mfma_f32_16x16x32_bf16(Af1, Bf[nt][1], acc[nt], 0, 0, 0);
        }
#pragma unroll
        for (int nt = 0; nt < 4; nt++){
#pragma unroll
            for (int r = 0; r < 4; r++){
                float v = acc[nt][r];
                xo[(m0 + quad*4 + r)*64 + nt*16 + col] = f2bf(v);
                ssum[nt] += v;
                ssq[nt] = fmaf(v, v, ssq[nt]);
            }
        }
    }
#pragma unroll
    for (int nt = 0; nt < 4; nt++){
        ssum[nt] += __shfl_xor(ssum[nt], 16); ssq[nt] += __shfl_xor(ssq[nt], 16);
        ssum[nt] += __shfl_xor(ssum[nt], 32); ssq[nt] += __shfl_xor(ssq[nt], 32);
    }
    if (quad == 0){
        float* st = stats + (blockIdx.x & 7)*256;
#pragma unroll
        for (int nt = 0; nt < 4; nt++){
            atomicAdd(&st[nt*16 + col], ssum[nt]);
            atomicAdd(&st[128 + nt*16 + col], ssq[nt]);
        }
    }
}

// ---------------- conv3 (MFMA): 64->128, in-block BN1 finalize, fused stats + group max/min ----------------
__global__ __launch_bounds__(256) void conv3_kernel(const u32* __restrict__ xin, const float* __restrict__ stats_in,
                                                    const float* __restrict__ gw, const float* __restrict__ beta,
                                                    const float* __restrict__ w, const float* __restrict__ bias,
                                                    float* __restrict__ gmax, float* __restrict__ gmin,
                                                    float* __restrict__ stats)
{
    __shared__ float saff[256];
    const int tid = threadIdx.x;
    block_finalize(stats_in, gw, beta, saff, 64, tid);
    const int lane = tid & 63;
    const int wid = tid >> 6;
    const int quad = lane >> 4;
    const int col = lane & 15;
    frag_ab Bf[8][2];
#pragma unroll
    for (int nt = 0; nt < 8; nt++)
#pragma unroll
        for (int kh = 0; kh < 2; kh++){
            const float* wr = w + (nt*16 + col)*64 + kh*32 + quad*8;
#pragma unroll
            for (int j = 0; j < 8; j++) Bf[nt][kh][j] = (short)f2bf(wr[j]);
        }
    float biasl[8];
#pragma unroll
    for (int nt = 0; nt < 8; nt++) biasl[nt] = bias[nt*16 + col];
    __syncthreads();
    float ak[2][8], bk[2][8];
#pragma unroll
    for (int kh = 0; kh < 2; kh++)
#pragma unroll
        for (int j = 0; j < 8; j++){
            int k = kh*32 + quad*8 + j;
            ak[kh][j] = saff[k]; bk[kh][j] = saff[128+k];
        }
    float ssum[8], ssq[8], mx[8], mn[8];
#pragma unroll
    for (int nt = 0; nt < 8; nt++){ ssum[nt] = 0.f; ssq[nt] = 0.f; }
    const int tile0 = blockIdx.x*32 + wid*8;
#pragma unroll 2
    for (int t = 0; t < 8; t++){
        const size_t m0 = (size_t)(tile0 + t) * 16;
        const u32* arow = xin + (m0 + col)*32;
        uint4 u0 = *(const uint4*)(arow + quad*4);
        uint4 u1 = *(const uint4*)(arow + 16 + quad*4);
        frag_ab Af0, Af1;
        unpack_affine_relu(u0, ak[0], bk[0], (short*)&Af0);
        unpack_affine_relu(u1, ak[1], bk[1], (short*)&Af1);
        frag_cd acc[8];
#pragma unroll
        for (int nt = 0; nt < 8; nt++){
            acc[nt] = (frag_cd){biasl[nt], biasl[nt], biasl[nt], biasl[nt]};
            acc[nt] = __builtin_amdgcn_mfma_f32_16x16x32_bf16(Af0, Bf[nt][0], acc[nt], 0, 0, 0);
            acc[nt] = __builtin_amdgcn_mfma_f32_16x16x32_bf16(Af1, Bf[nt][1], acc[nt], 0, 0, 0);
        }
#pragma unroll
        for (int nt = 0; nt < 8; nt++){
            float a0 = fmaxf(fmaxf(acc[nt][0], acc[nt][1]), fmaxf(acc[nt][2], acc[nt][3]));
            float n0 = fminf(fminf(acc[nt][0], acc[nt][1]), fminf(acc[nt][2], acc[nt][3]));
            if ((t & 1) == 0){ mx[nt] = a0; mn[nt] = n0; }
            else { mx[nt] = fmaxf(mx[nt], a0); mn[nt] = fminf(mn[nt], n0); }
#pragma unroll
            for (int r = 0; r < 4; r++){
                float v = acc[nt][r];
                ssum[nt] += v;
                ssq[nt] = fmaf(v, v, ssq[nt]);
            }
        }
        if (t & 1){
#pragma unroll
            for (int nt = 0; nt < 8; nt++){
                mx[nt] = fmaxf(mx[nt], __shfl_xor(mx[nt], 16));
                mn[nt] = fminf(mn[nt], __shfl_xor(mn[nt], 16));
                mx[nt] = fmaxf(mx[nt], __shfl_xor(mx[nt], 32));
                mn[nt] = fminf(mn[nt], __shfl_xor(mn[nt], 32));
            }
            if (quad == 0){
                const int g = (tile0 + t - 1) >> 1;
#pragma unroll
                for (int nt = 0; nt < 8; nt++){
                    gmax[(size_t)g*128 + nt*16 + col] = mx[nt];
                    gmin[(size_t)g*128 + nt*16 + col] = mn[nt];
                }
            }
        }
    }
#pragma unroll
    for (int nt = 0; nt < 8; nt++){
        ssum[nt] += __shfl_xor(ssum[nt], 16); ssq[nt] += __shfl_xor(ssq[nt], 16);
        ssum[nt] += __shfl_xor(ssum[nt], 32); ssq[nt] += __shfl_xor(ssq[nt], 32);
    }
    if (quad == 0){
        float* st = stats + (blockIdx.x & 7)*256;
#pragma unroll
        for (int nt = 0; nt < 8; nt++){
            atomicAdd(&st[nt*16 + col], ssum[nt]);
            atomicAdd(&st[128 + nt*16 + col], ssq[nt]);
        }
    }
}

// ---------------- pool: in-block BN2 finalize + relu from group max/min ----------------
__global__ __launch_bounds__(256) void pool_kernel(const float* __restrict__ gmax, const float* __restrict__ gmin,
                                                   const float* __restrict__ stats_in, const float* __restrict__ gw,
                                                   const float* __restrict__ beta, float* __restrict__ out)
{
    __shared__ float saff[256];
    const int tid = threadIdx.x;
    block_finalize(stats_in, gw, beta, saff, 128, tid);
    __syncthreads();
    const int base = blockIdx.x*2048 + tid;
#pragma unroll
    for (int k = 0; k < 8; k++){
        int idx = base + k*256;
        int o = idx & 127;
        float a = saff[o], bsh = saff[128+o];
        float v = (a >= 0.f) ? fmaf(a, gmax[idx], bsh) : fmaf(a, gmin[idx], bsh);
        out[(size_t)BB*NPOINT*3 + idx] = fmaxf(v, 0.f);
    }
}

extern "C" void kernel_launch(void* const* d_in, const int* in_sizes, int n_in,
                              void* d_out, int out_size, void* d_ws, size_t ws_size,
                              hipStream_t stream)
{
    const float* xyz    = (const float*)d_in[0];
    const float* points = (const float*)d_in[1];
    const float* w0  = (const float*)d_in[2];
    const float* b0  = (const float*)d_in[3];
    const float* g0  = (const float*)d_in[4];
    const float* be0 = (const float*)d_in[5];
    const float* w1  = (const float*)d_in[6];
    const float* b1  = (const float*)d_in[7];
    const float* g1  = (const float*)d_in[8];
    const float* be1 = (const float*)d_in[9];
    const float* w2  = (const float*)d_in[10];
    const float* b2  = (const float*)d_in[11];
    const float* g2  = (const float*)d_in[12];
    const float* be2 = (const float*)d_in[13];
    float* out = (float*)d_out;
    char* ws = (char*)d_ws;

    int*   cents    = (int*)(ws + 0);              //  64 KiB
    int*   gidx     = (int*)(ws + 262144);         //   2 MiB -> ends 2359296
    float* stats    = (float*)(ws + 2359296);      //  24 KiB (3 layers x 8 replicas x 256 f)
    int*   progress = (int*)(ws + 2383872);        //  16 ints
    int*   packdone = (int*)(ws + 2383936);        //   1 int
    u32*   x1buf    = (u32*)(ws + 2386944);        //  64 MiB (conv1 out bf16)
    u32*   x2buf    = (u32*)(ws + 69495808);       //  64 MiB (conv2 out bf16)
    float* gmax     = (float*)(ws + 136604672);    // 8.4 MiB (conv3 out; aliases pbf - dead by then)
    float* gmin     = (float*)(ws + 144993280);    // 8.4 MiB
    u32*   pbf      = (u32*)(ws + 136604672);      // 8.4 MiB packed bf16 points (dead after mega)

    // zero stats (24 KiB) + progress + packdone
    hipMemsetAsync(ws + 2359296, 0, 24576 + 128, stream);
    mega_kernel<<<256, 256, 0, stream>>>(xyz, points, w0, b0, cents, pbf, gidx, out,
                                         stats, progress, packdone, x1buf);
    conv2_kernel<<<512, 256, 0, stream>>>(x1buf, stats, g0, be0, w1, b1, x2buf, stats + 2048);
    conv3_kernel<<<1024, 256, 0, stream>>>(x2buf, stats + 2048, g1, be1, w2, b2, gmax, gmin, stats + 4096);
    pool_kernel<<<1024, 256, 0, stream>>>(gmax, gmin, stats + 4096, g2, be2, out);
}

// Round 10
// 750.604 us; speedup vs baseline: 1.7642x; 1.7642x over previous
//
#include <hip/hip_runtime.h>
#include <hip/hip_bf16.h>
#include <stdint.h>

#define BB 16
#define NN 4096
#define NPOINT 1024
#define NSAMPLE 32

typedef unsigned int u32;
typedef unsigned long long u64;
typedef unsigned short u16;
typedef float f32x2 __attribute__((ext_vector_type(2)));
using frag_ab = __attribute__((ext_vector_type(8))) short;   // 8 bf16 (4 VGPRs)
using frag_cd = __attribute__((ext_vector_type(4))) float;   // 4 fp32

__device__ inline u16 f2bf(float x){ u32 u = __float_as_uint(x); u32 r = (u + 0x7fffu + ((u>>16)&1u)) >> 16; return (u16)r; }
__device__ inline float bf2f(u32 hbits){ return __uint_as_float(hbits<<16); }
__device__ inline u64 umax64(u64 a, u64 b){ return a > b ? a : b; }

// full-wave (64-lane) f32 max via DPP; result bits returned from lane 63.
__device__ inline int wave_max_bits(float v){
    int x = __float_as_int(v);
    int t;
    t = __builtin_amdgcn_update_dpp(0, x, 0x111, 0xf, 0xf, true);  // row_shr:1
    x = __float_as_int(fmaxf(__int_as_float(x), __int_as_float(t)));
    t = __builtin_amdgcn_update_dpp(0, x, 0x112, 0xf, 0xf, true);  // row_shr:2
    x = __float_as_int(fmaxf(__int_as_float(x), __int_as_float(t)));
    t = __builtin_amdgcn_update_dpp(0, x, 0x114, 0xf, 0xf, true);  // row_shr:4
    x = __float_as_int(fmaxf(__int_as_float(x), __int_as_float(t)));
    t = __builtin_amdgcn_update_dpp(0, x, 0x118, 0xf, 0xf, true);  // row_shr:8
    x = __float_as_int(fmaxf(__int_as_float(x), __int_as_float(t)));
    t = __builtin_amdgcn_update_dpp(0, x, 0x142, 0xf, 0xf, true);  // row_bcast:15
    x = __float_as_int(fmaxf(__int_as_float(x), __int_as_float(t)));
    t = __builtin_amdgcn_update_dpp(0, x, 0x143, 0xf, 0xf, true);  // row_bcast:31
    x = __float_as_int(fmaxf(__int_as_float(x), __int_as_float(t)));
    return __builtin_amdgcn_readlane(x, 63);
}

// ---------------- points -> packed bf16 (separate kernel: boundary gives pbf visibility) ----------------
__global__ __launch_bounds__(256) void pack_points_kernel(const float* __restrict__ points, u32* __restrict__ pbf)
{
    int i = blockIdx.x*256 + threadIdx.x;   // < 2097152
    float f0 = points[2*i], f1 = points[2*i+1];
    pbf[i] = (u32)f2bf(f0) | ((u32)f2bf(f1) << 16);
}

// ================= MEGA: blocks 0..15 = FPS (R3-exact; publishes cents via RELAXED agent
// ================= atomic store = cache-bypass, no fences). blocks 16..127 = workers:
// ================= per-centroid poll (RELAXED agent load) -> new_xyz + ballquery + conv1.
// 128 blocks on 256 CUs -> 1 block/CU, fps CUs isolated. No acquire/release/threadfence
// in any hot path (R9 post-mortem: those lower to L2 wb/inv storms on gfx950).
__global__ __launch_bounds__(256) void mega_kernel(const float* __restrict__ xyz, const u32* __restrict__ pbf,
    const float* __restrict__ w0, const float* __restrict__ bias0,
    int* __restrict__ cents, int* __restrict__ gidx,
    float* __restrict__ out, float* __restrict__ stats, u32* __restrict__ x1buf)
{
#pragma clang fp contract(off)
    __shared__ float lxyz[NN*3];
    __shared__ __align__(16) u64 s_red[2][4];
    const int tid = threadIdx.x;
    const int lane = tid & 63;
    const int wid = tid >> 6;

    if (blockIdx.x < 16){
        // ---------------- FPS (R3-exact structure, 544us measured) ----------------
        const int b = blockIdx.x;
        const float* gx = xyz + (size_t)b*NN*3;
        for (int i = tid; i < NN*3; i += 256) lxyz[i] = gx[i];
        __syncthreads();
        f32x2 px[8], py[8], pz[8], dist[8];
#pragma unroll
        for (int jj = 0; jj < 8; jj++){
            int p = tid*16 + jj*2;
            px[jj] = (f32x2){ lxyz[p*3+0], lxyz[(p+1)*3+0] };
            py[jj] = (f32x2){ lxyz[p*3+1], lxyz[(p+1)*3+1] };
            pz[jj] = (f32x2){ lxyz[p*3+2], lxyz[(p+1)*3+2] };
            dist[jj] = (f32x2){ 1e10f, 1e10f };
        }
        int far = 0, par = 0;
        for (int s = 0; s < NPOINT; s++){
            if (tid == 0)   // relaxed agent store: bypasses L2 to coherent point; no wb/inv
                __hip_atomic_store(&cents[b*NPOINT + s], far, __ATOMIC_RELAXED, __HIP_MEMORY_SCOPE_AGENT);
            float cx = lxyz[far*3+0], cy = lxyz[far*3+1], cz = lxyz[far*3+2];
            f32x2 c2x = { cx, cx }, c2y = { cy, cy }, c2z = { cz, cz };
            float bv = -1.0f; int bj = 0;
#pragma unroll
            for (int jj = 0; jj < 8; jj++){
                f32x2 dx = px[jj] - c2x;
                f32x2 dy = py[jj] - c2y;
                f32x2 dz = pz[jj] - c2z;
                f32x2 d  = (dx*dx + dy*dy) + dz*dz;     // contract(off): exact _rn order
                f32x2 nd;
                nd.x = fminf(dist[jj].x, d.x);
                nd.y = fminf(dist[jj].y, d.y);
                dist[jj] = nd;
                if (nd.x > bv){ bv = nd.x; bj = jj*2; }       // ascending j => first-max kept
                if (nd.y > bv){ bv = nd.y; bj = jj*2+1; }
            }
            int wmb = wave_max_bits(bv);
            float wmax = __int_as_float(wmb);
            u64 mask = __ballot(bv == wmax);
            int fl = __ffsll((long long)mask) - 1;             // lowest lane => lowest p
            int fj = __builtin_amdgcn_readlane(bj, fl);
            int p = (wid << 10) + (fl << 4) + fj;
            if (lane == 0) s_red[par][wid] = ((u64)(u32)wmb << 32) | (u32)(4095 - p);
            __syncthreads();
            u64 m0 = umax64(s_red[par][0], s_red[par][1]);
            u64 m1 = umax64(s_red[par][2], s_red[par][3]);
            u64 m  = umax64(m0, m1);
            far = 4095 - (int)(m & 0xFFFu);
            par ^= 1;
        }
    } else {
        // ---------------- workers: 112 blocks = 448 waves ----------------
        const int w = (blockIdx.x - 16)*4 + wid;   // 0..447
        const int quad = lane >> 4;
        const int col = lane & 15;
        frag_ab Bf[4][2];
#pragma unroll
        for (int nt = 0; nt < 4; nt++)
#pragma unroll
            for (int kh = 0; kh < 2; kh++){
                const float* wr = w0 + (nt*16 + col)*67 + 3 + kh*32 + quad*8;
#pragma unroll
                for (int j = 0; j < 8; j++) Bf[nt][kh][j] = (short)f2bf(wr[j]);
            }
        float wx[4], wy[4], wz[4], biasl[4];
#pragma unroll
        for (int nt = 0; nt < 4; nt++){
            const float* wb = w0 + (nt*16 + col)*67;
            wx[nt] = wb[0]; wy[nt] = wb[1]; wz[nt] = wb[2];
            biasl[nt] = bias0[nt*16 + col];
        }
        float ssum[4] = {0,0,0,0}, ssq[4] = {0,0,0,0};
        u16* xo = (u16*)x1buf;
        const float RAD2 = (float)(0.9*0.9);
        const int b = w & 15;                       // 28 waves per batch
        const float* gx = xyz + (size_t)b*NN*3;
        for (int s = (w >> 4); s < NPOINT; s += 28){
            const int g = (b << 10) + s;
            int ci;
            while ((ci = __hip_atomic_load(&cents[g], __ATOMIC_RELAXED, __HIP_MEMORY_SCOPE_AGENT)) == -1)
                __builtin_amdgcn_s_sleep(32);
            const float* cp = xyz + ((size_t)b*NN + ci)*3;
            float cx = cp[0], cy = cp[1], cz = cp[2];
            if (lane < 3) out[g*3 + lane] = cp[lane];   // new_xyz output
            // ---- ball query (verbatim math) ----
            float sc = __fadd_rn(__fadd_rn(__fmul_rn(cx,cx), __fmul_rn(cy,cy)), __fmul_rn(cz,cz));
            int* gout = gidx + (size_t)g*NSAMPLE;
            int found = 0; int first = -1;
            for (int base = 0; base < NN; base += 64){
                int i = base + lane;
                float pxv = gx[i*3+0], pyv = gx[i*3+1], pzv = gx[i*3+2];
                float sp = __fadd_rn(__fadd_rn(__fmul_rn(pxv,pxv), __fmul_rn(pyv,pyv)), __fmul_rn(pzv,pzv));
                float dot = __fadd_rn(__fadd_rn(__fmul_rn(cx,pxv), __fmul_rn(cy,pyv)), __fmul_rn(cz,pzv));
                float d2 = __fsub_rn(__fadd_rn(sc, sp), __fmul_rn(2.0f, dot));
                float dd = __fsqrt_rn(fmaxf(d2, 0.0f));
                bool in = !(dd > RAD2);
                u64 m = __ballot(in);
                int cnt = __popcll(m);
                if (in){
                    int slot = found + __popcll(m & ((1ull<<lane) - 1ull));
                    if (slot < NSAMPLE) gout[slot] = i;
                }
                if (found == 0 && cnt > 0) first = base + (__ffsll(m) - 1);
                found += cnt;
                if (found >= NSAMPLE) break;
            }
            if (found < NSAMPLE){
                if (found == 0) first = ci;
                for (int slot = found + lane; slot < NSAMPLE; slot += 64) gout[slot] = first;
            }
            // own-wave gidx stores -> own-wave loads: drain own VMEM (same-address L1 path);
            // NOT a __threadfence (R9: agent fences = L2 wb/inv storm)
            asm volatile("s_waitcnt vmcnt(0)" ::: "memory");
            // ---- conv1 for this centroid's 32 rows (2 MFMA tiles) ----
#pragma unroll
            for (int t = 0; t < 2; t++){
                const int m0 = g*32 + t*16;
                const int gg = gidx[m0 + col];
                const u32* arow = pbf + ((size_t)(b<<12) + gg)*32;
                uint4 u0 = *(const uint4*)(arow + quad*4);
                uint4 u1 = *(const uint4*)(arow + 16 + quad*4);
                frag_ab Af0, Af1;
                __builtin_memcpy(&Af0, &u0, 16);
                __builtin_memcpy(&Af1, &u1, 16);
                frag_cd acc[4];
#pragma unroll
                for (int nt = 0; nt < 4; nt++){
                    acc[nt] = (frag_cd){0.f, 0.f, 0.f, 0.f};
                    acc[nt] = __builtin_amdgcn_mfma_f32_16x16x32_bf16(Af0, Bf[nt][0], acc[nt], 0, 0, 0);
                    acc[nt] = __builtin_amdgcn_mfma_f32_16x16x32_bf16(Af1, Bf[nt][1], acc[nt], 0, 0, 0);
                }
#pragma unroll
                for (int r = 0; r < 4; r++){
                    const int rowm = m0 + quad*4 + r;
                    const int pt = gidx[rowm];
                    const float* p3 = xyz + ((size_t)(b<<12) + pt)*3;
                    float xnx = p3[0]-cx, xny = p3[1]-cy, xnz = p3[2]-cz;
#pragma unroll
                    for (int nt = 0; nt < 4; nt++){
                        float v = acc[nt][r] + biasl[nt];
                        v = fmaf(wx[nt], xnx, v);
                        v = fmaf(wy[nt], xny, v);
                        v = fmaf(wz[nt], xnz, v);
                        xo[(size_t)rowm*64 + nt*16 + col] = f2bf(v);
                        ssum[nt] += v;
                        ssq[nt] = fmaf(v, v, ssq[nt]);
                    }
                }
            }
        }
        // stats reduce (lanes sharing col) + global atomics (device-scope, coherent)
#pragma unroll
        for (int nt = 0; nt < 4; nt++){
            ssum[nt] += __shfl_xor(ssum[nt], 16); ssq[nt] += __shfl_xor(ssq[nt], 16);
            ssum[nt] += __shfl_xor(ssum[nt], 32); ssq[nt] += __shfl_xor(ssq[nt], 32);
        }
        if (quad == 0){
            float* st = stats + (blockIdx.x & 7)*256;
#pragma unroll
            for (int nt = 0; nt < 4; nt++){
                atomicAdd(&st[nt*16 + col], ssum[nt]);
                atomicAdd(&st[128 + nt*16 + col], ssq[nt]);
            }
        }
    }
}

// ---- in-block BN finalize: stats (8 replicas) + g/beta -> saff[a:0..127 | b:128..255] ----
__device__ inline void block_finalize(const float* __restrict__ stats, const float* __restrict__ g,
                                      const float* __restrict__ beta, float* saff, int C, int tid)
{
    if (tid < C){
        float sm = 0.f, sq = 0.f;
#pragma unroll
        for (int r = 0; r < 8; r++){ sm += stats[r*256+tid]; sq += stats[r*256+128+tid]; }
        const float invM = 1.0f / 524288.0f;
        float mu  = sm * invM;
        float var = fmaxf(sq * invM - mu*mu, 0.0f);
        float inv = 1.0f / sqrtf(var + 1e-5f);
        float a = g[tid] * inv;
        saff[tid] = a;
        saff[128+tid] = beta[tid] - mu*a;
    }
}

// ---- unpack 8 packed-bf16, apply affine+relu, emit bf16 frag half ----
__device__ inline void unpack_affine_relu(uint4 u, const float* ak, const float* bk, short* dst){
    const u32* uu = (const u32*)&u;
#pragma unroll
    for (int q = 0; q < 4; q++){
        u32 v = uu[q];
        float x0 = bf2f(v & 0xffffu);
        float x1 = bf2f(v >> 16);
        float f0 = fmaxf(fmaf(ak[2*q],   x0, bk[2*q]),   0.f);
        float f1 = fmaxf(fmaf(ak[2*q+1], x1, bk[2*q+1]), 0.f);
        dst[2*q]   = (short)f2bf(f0);
        dst[2*q+1] = (short)f2bf(f1);
    }
}

// ---------------- conv2 (MFMA): 64->64, in-block BN0 finalize, BN+relu on load, fused stats ----------------
__global__ __launch_bounds__(256) void conv2_kernel(const u32* __restrict__ xin, const float* __restrict__ stats_in,
                                                    const float* __restrict__ gw, const float* __restrict__ beta,
                                                    const float* __restrict__ w, const float* __restrict__ bias,
                                                    u32* __restrict__ xout, float* __restrict__ stats)
{
    __shared__ float saff[256];
    const int tid = threadIdx.x;
    block_finalize(stats_in, gw, beta, saff, 64, tid);
    const int lane = tid & 63;
    const int wid = tid >> 6;
    const int quad = lane >> 4;
    const int col = lane & 15;
    frag_ab Bf[4][2];
#pragma unroll
    for (int nt = 0; nt < 4; nt++)
#pragma unroll
        for (int kh = 0; kh < 2; kh++){
            const float* wr = w + (nt*16 + col)*64 + kh*32 + quad*8;
#pragma unroll
            for (int j = 0; j < 8; j++) Bf[nt][kh][j] = (short)f2bf(wr[j]);
        }
    float biasl[4];
#pragma unroll
    for (int nt = 0; nt < 4; nt++) biasl[nt] = bias[nt*16 + col];
    __syncthreads();
    float ak[2][8], bk[2][8];
#pragma unroll
    for (int kh = 0; kh < 2; kh++)
#pragma unroll
        for (int j = 0; j < 8; j++){
            int k = kh*32 + quad*8 + j;
            ak[kh][j] = saff[k]; bk[kh][j] = saff[128+k];
        }
    float ssum[4] = {0,0,0,0}, ssq[4] = {0,0,0,0};
    u16* xo = (u16*)xout;
    const int tile0 = blockIdx.x*64 + wid*16;
    for (int t = 0; t < 16; t++){
        const size_t m0 = (size_t)(tile0 + t) * 16;
        const u32* arow = xin + (m0 + col)*32;
        uint4 u0 = *(const uint4*)(arow + quad*4);
        uint4 u1 = *(const uint4*)(arow + 16 + quad*4);
        frag_ab Af0, Af1;
        unpack_affine_relu(u0, ak[0], bk[0], (short*)&Af0);
        unpack_affine_relu(u1, ak[1], bk[1], (short*)&Af1);
        frag_cd acc[4];
#pragma unroll
        for (int nt = 0; nt < 4; nt++){
            acc[nt] = (frag_cd){biasl[nt], biasl[nt], biasl[nt], biasl[nt]};
            acc[nt] = __builtin_amdgcn_mfma_f32_16x16x32_bf16(Af0, Bf[nt][0], acc[nt], 0, 0, 0);
            acc[nt] = __builtin_amdgcn_mfma_f32_16x16x32_bf16(Af1, Bf[nt][1], acc[nt], 0, 0, 0);
        }
#pragma unroll
        for (int nt = 0; nt < 4; nt++){
#pragma unroll
            for (int r = 0; r < 4; r++){
                float v = acc[nt][r];
                xo[(m0 + quad*4 + r)*64 + nt*16 + col] = f2bf(v);
                ssum[nt] += v;
                ssq[nt] = fmaf(v, v, ssq[nt]);
            }
        }
    }
#pragma unroll
    for (int nt = 0; nt < 4; nt++){
        ssum[nt] += __shfl_xor(ssum[nt], 16); ssq[nt] += __shfl_xor(ssq[nt], 16);
        ssum[nt] += __shfl_xor(ssum[nt], 32); ssq[nt] += __shfl_xor(ssq[nt], 32);
    }
    if (quad == 0){
        float* st = stats + (blockIdx.x & 7)*256;
#pragma unroll
        for (int nt = 0; nt < 4; nt++){
            atomicAdd(&st[nt*16 + col], ssum[nt]);
            atomicAdd(&st[128 + nt*16 + col], ssq[nt]);
        }
    }
}

// ---------------- conv3 (MFMA): 64->128, in-block BN1 finalize, fused stats + group max/min ----------------
__global__ __launch_bounds__(256) void conv3_kernel(const u32* __restrict__ xin, const float* __restrict__ stats_in,
                                                    const float* __restrict__ gw, const float* __restrict__ beta,
                                                    const float* __restrict__ w, const float* __restrict__ bias,
                                                    float* __restrict__ gmax, float* __restrict__ gmin,
                                                    float* __restrict__ stats)
{
    __shared__ float saff[256];
    const int tid = threadIdx.x;
    block_finalize(stats_in, gw, beta, saff, 64, tid);
    const int lane = tid & 63;
    const int wid = tid >> 6;
    const int quad = lane >> 4;
    const int col = lane & 15;
    frag_ab Bf[8][2];
#pragma unroll
    for (int nt = 0; nt < 8; nt++)
#pragma unroll
        for (int kh = 0; kh < 2; kh++){
            const float* wr = w + (nt*16 + col)*64 + kh*32 + quad*8;
#pragma unroll
            for (int j = 0; j < 8; j++) Bf[nt][kh][j] = (short)f2bf(wr[j]);
        }
    float biasl[8];
#pragma unroll
    for (int nt = 0; nt < 8; nt++) biasl[nt] = bias[nt*16 + col];
    __syncthreads();
    float ak[2][8], bk[2][8];
#pragma unroll
    for (int kh = 0; kh < 2; kh++)
#pragma unroll
        for (int j = 0; j < 8; j++){
            int k = kh*32 + quad*8 + j;
            ak[kh][j] = saff[k]; bk[kh][j] = saff[128+k];
        }
    float ssum[8], ssq[8], mx[8], mn[8];
#pragma unroll
    for (int nt = 0; nt < 8; nt++){ ssum[nt] = 0.f; ssq[nt] = 0.f; }
    const int tile0 = blockIdx.x*32 + wid*8;
#pragma unroll 2
    for (int t = 0; t < 8; t++){
        const size_t m0 = (size_t)(tile0 + t) * 16;
        const u32* arow = xin + (m0 + col)*32;
        uint4 u0 = *(const uint4*)(arow + quad*4);
        uint4 u1 = *(const uint4*)(arow + 16 + quad*4);
        frag_ab Af0, Af1;
        unpack_affine_relu(u0, ak[0], bk[0], (short*)&Af0);
        unpack_affine_relu(u1, ak[1], bk[1], (short*)&Af1);
        frag_cd acc[8];
#pragma unroll
        for (int nt = 0; nt < 8; nt++){
            acc[nt] = (frag_cd){biasl[nt], biasl[nt], biasl[nt], biasl[nt]};
            acc[nt] = __builtin_amdgcn_mfma_f32_16x16x32_bf16(Af0, Bf[nt][0], acc[nt], 0, 0, 0);
            acc[nt] = __builtin_amdgcn_mfma_f32_16x16x32_bf16(Af1, Bf[nt][1], acc[nt], 0, 0, 0);
        }
#pragma unroll
        for (int nt = 0; nt < 8; nt++){
            float a0 = fmaxf(fmaxf(acc[nt][0], acc[nt][1]), fmaxf(acc[nt][2], acc[nt][3]));
            float n0 = fminf(fminf(acc[nt][0], acc[nt][1]), fminf(acc[nt][2], acc[nt][3]));
            if ((t & 1) == 0){ mx[nt] = a0; mn[nt] = n0; }
            else { mx[nt] = fmaxf(mx[nt], a0); mn[nt] = fminf(mn[nt], n0); }
#pragma unroll
            for (int r = 0; r < 4; r++){
                float v = acc[nt][r];
                ssum[nt] += v;
                ssq[nt] = fmaf(v, v, ssq[nt]);
            }
        }
        if (t & 1){
#pragma unroll
            for (int nt = 0; nt < 8; nt++){
                mx[nt] = fmaxf(mx[nt], __shfl_xor(mx[nt], 16));
                mn[nt] = fminf(mn[nt], __shfl_xor(mn[nt], 16));
                mx[nt] = fmaxf(mx[nt], __shfl_xor(mx[nt], 32));
                mn[nt] = fminf(mn[nt], __shfl_xor(mn[nt], 32));
            }
            if (quad == 0){
                const int g = (tile0 + t - 1) >> 1;
#pragma unroll
                for (int nt = 0; nt < 8; nt++){
                    gmax[(size_t)g*128 + nt*16 + col] = mx[nt];
                    gmin[(size_t)g*128 + nt*16 + col] = mn[nt];
                }
            }
        }
    }
#pragma unroll
    for (int nt = 0; nt < 8; nt++){
        ssum[nt] += __shfl_xor(ssum[nt], 16); ssq[nt] += __shfl_xor(ssq[nt], 16);
        ssum[nt] += __shfl_xor(ssum[nt], 32); ssq[nt] += __shfl_xor(ssq[nt], 32);
    }
    if (quad == 0){
        float* st = stats + (blockIdx.x & 7)*256;
#pragma unroll
        for (int nt = 0; nt < 8; nt++){
            atomicAdd(&st[nt*16 + col], ssum[nt]);
            atomicAdd(&st[128 + nt*16 + col], ssq[nt]);
        }
    }
}

// ---------------- pool: in-block BN2 finalize + relu from group max/min ----------------
__global__ __launch_bounds__(256) void pool_kernel(const float* __restrict__ gmax, const float* __restrict__ gmin,
                                                   const float* __restrict__ stats_in, const float* __restrict__ gw,
                                                   const float* __restrict__ beta, float* __restrict__ out)
{
    __shared__ float saff[256];
    const int tid = threadIdx.x;
    block_finalize(stats_in, gw, beta, saff, 128, tid);
    __syncthreads();
    const int base = blockIdx.x*2048 + tid;
#pragma unroll
    for (int k = 0; k < 8; k++){
        int idx = base + k*256;
        int o = idx & 127;
        float a = saff[o], bsh = saff[128+o];
        float v = (a >= 0.f) ? fmaf(a, gmax[idx], bsh) : fmaf(a, gmin[idx], bsh);
        out[(size_t)BB*NPOINT*3 + idx] = fmaxf(v, 0.f);
    }
}

extern "C" void kernel_launch(void* const* d_in, const int* in_sizes, int n_in,
                              void* d_out, int out_size, void* d_ws, size_t ws_size,
                              hipStream_t stream)
{
    const float* xyz    = (const float*)d_in[0];
    const float* points = (const float*)d_in[1];
    const float* w0  = (const float*)d_in[2];
    const float* b0  = (const float*)d_in[3];
    const float* g0  = (const float*)d_in[4];
    const float* be0 = (const float*)d_in[5];
    const float* w1  = (const float*)d_in[6];
    const float* b1  = (const float*)d_in[7];
    const float* g1  = (const float*)d_in[8];
    const float* be1 = (const float*)d_in[9];
    const float* w2  = (const float*)d_in[10];
    const float* b2  = (const float*)d_in[11];
    const float* g2  = (const float*)d_in[12];
    const float* be2 = (const float*)d_in[13];
    float* out = (float*)d_out;
    char* ws = (char*)d_ws;

    int*   cents = (int*)(ws + 0);                 //  64 KiB (memset 0xFF = -1 sentinel)
    int*   gidx  = (int*)(ws + 262144);            //   2 MiB -> ends 2359296
    float* stats = (float*)(ws + 2359296);         //  24 KiB (3 layers x 8 replicas x 256 f)
    u32*   x1buf = (u32*)(ws + 2386944);           //  64 MiB (conv1 out bf16)
    u32*   x2buf = (u32*)(ws + 69495808);          //  64 MiB (conv2 out bf16)
    float* gmax  = (float*)(ws + 136604672);       // 8.4 MiB (conv3 out; aliases pbf - dead by then)
    float* gmin  = (float*)(ws + 144993280);       // 8.4 MiB
    u32*   pbf   = (u32*)(ws + 136604672);         // 8.4 MiB packed bf16 points (dead after mega)

    hipMemsetAsync(cents, 0xFF, NPOINT*BB*sizeof(int), stream);   // -1 sentinels
    hipMemsetAsync(stats, 0, 6144*sizeof(float), stream);
    pack_points_kernel<<<8192, 256, 0, stream>>>(points, pbf);
    mega_kernel<<<128, 256, 0, stream>>>(xyz, pbf, w0, b0, cents, gidx, out, stats, x1buf);
    conv2_kernel<<<512, 256, 0, stream>>>(x1buf, stats, g0, be0, w1, b1, x2buf, stats + 2048);
    conv3_kernel<<<1024, 256, 0, stream>>>(x2buf, stats + 2048, g1, be1, w2, b2, gmax, gmin, stats + 4096);
    pool_kernel<<<1024, 256, 0, stream>>>(gmax, gmin, stats + 4096, g2, be2, out);
}

// Round 11
// 740.887 us; speedup vs baseline: 1.7874x; 1.0131x over previous
//
#include <hip/hip_runtime.h>
#include <hip/hip_bf16.h>
#include <stdint.h>

#define BB 16
#define NN 4096
#define NPOINT 1024
#define NSAMPLE 32

typedef unsigned int u32;
typedef unsigned long long u64;
typedef unsigned short u16;
typedef float f32x2 __attribute__((ext_vector_type(2)));
using frag_ab = __attribute__((ext_vector_type(8))) short;   // 8 bf16 (4 VGPRs)
using frag_cd = __attribute__((ext_vector_type(4))) float;   // 4 fp32

__device__ inline u16 f2bf(float x){ u32 u = __float_as_uint(x); u32 r = (u + 0x7fffu + ((u>>16)&1u)) >> 16; return (u16)r; }
__device__ inline float bf2f(u32 hbits){ return __uint_as_float(hbits<<16); }
__device__ inline u64 umax64(u64 a, u64 b){ return a > b ? a : b; }

// full-wave (64-lane) f32 max via DPP; result bits returned from lane 63.
__device__ inline int wave_max_bits(float v){
    int x = __float_as_int(v);
    int t;
    t = __builtin_amdgcn_update_dpp(0, x, 0x111, 0xf, 0xf, true);  // row_shr:1
    x = __float_as_int(fmaxf(__int_as_float(x), __int_as_float(t)));
    t = __builtin_amdgcn_update_dpp(0, x, 0x112, 0xf, 0xf, true);  // row_shr:2
    x = __float_as_int(fmaxf(__int_as_float(x), __int_as_float(t)));
    t = __builtin_amdgcn_update_dpp(0, x, 0x114, 0xf, 0xf, true);  // row_shr:4
    x = __float_as_int(fmaxf(__int_as_float(x), __int_as_float(t)));
    t = __builtin_amdgcn_update_dpp(0, x, 0x118, 0xf, 0xf, true);  // row_shr:8
    x = __float_as_int(fmaxf(__int_as_float(x), __int_as_float(t)));
    t = __builtin_amdgcn_update_dpp(0, x, 0x142, 0xf, 0xf, true);  // row_bcast:15
    x = __float_as_int(fmaxf(__int_as_float(x), __int_as_float(t)));
    t = __builtin_amdgcn_update_dpp(0, x, 0x143, 0xf, 0xf, true);  // row_bcast:31
    x = __float_as_int(fmaxf(__int_as_float(x), __int_as_float(t)));
    return __builtin_amdgcn_readlane(x, 63);
}

// ================= MEGA: blocks 0..15 = FPS (R8 structure, but in-loop barrier is
// ================= `s_waitcnt lgkmcnt(0); s_barrier` — does NOT drain the cents store).
// ================= blocks 16..127 = workers: poll cents (RELAXED agent) -> new_xyz +
// ================= ballquery + conv1 (fp32 points gathered directly, no pack kernel).
__global__ __launch_bounds__(256) void mega_kernel(const float* __restrict__ xyz, const float* __restrict__ points,
    const float* __restrict__ w0, const float* __restrict__ bias0,
    int* __restrict__ cents, int* __restrict__ gidx,
    float* __restrict__ out, float* __restrict__ stats, u32* __restrict__ x1buf)
{
#pragma clang fp contract(off)
    __shared__ float lxyz[NN*3];
    __shared__ __align__(16) u64 s_red[2][4];
    const int tid = threadIdx.x;
    const int lane = tid & 63;
    const int wid = tid >> 6;

    if (blockIdx.x < 16){
        // ---------------- FPS ----------------
        const int b = blockIdx.x;
        const float* gx = xyz + (size_t)b*NN*3;
        for (int i = tid; i < NN*3; i += 256) lxyz[i] = gx[i];
        __syncthreads();
        f32x2 px[8], py[8], pz[8], dist[8];
#pragma unroll
        for (int jj = 0; jj < 8; jj++){
            int p = tid*16 + jj*2;
            px[jj] = (f32x2){ lxyz[p*3+0], lxyz[(p+1)*3+0] };
            py[jj] = (f32x2){ lxyz[p*3+1], lxyz[(p+1)*3+1] };
            pz[jj] = (f32x2){ lxyz[p*3+2], lxyz[(p+1)*3+2] };
            dist[jj] = (f32x2){ 1e10f, 1e10f };
        }
        int far = 0, par = 0;
        for (int s = 0; s < NPOINT; s++){
            if (tid == 0)   // relaxed agent store: bypass, never waited on (asm barrier skips vmcnt)
                __hip_atomic_store(&cents[b*NPOINT + s], far, __ATOMIC_RELAXED, __HIP_MEMORY_SCOPE_AGENT);
            float cx = lxyz[far*3+0], cy = lxyz[far*3+1], cz = lxyz[far*3+2];
            f32x2 c2x = { cx, cx }, c2y = { cy, cy }, c2z = { cz, cz };
            float bv = -1.0f; int bj = 0;
#pragma unroll
            for (int jj = 0; jj < 8; jj++){
                f32x2 dx = px[jj] - c2x;
                f32x2 dy = py[jj] - c2y;
                f32x2 dz = pz[jj] - c2z;
                f32x2 d  = (dx*dx + dy*dy) + dz*dz;     // contract(off): exact _rn order
                f32x2 nd;
                nd.x = fminf(dist[jj].x, d.x);
                nd.y = fminf(dist[jj].y, d.y);
                dist[jj] = nd;
                if (nd.x > bv){ bv = nd.x; bj = jj*2; }       // ascending j => first-max kept
                if (nd.y > bv){ bv = nd.y; bj = jj*2+1; }
            }
            int wmb = wave_max_bits(bv);
            float wmax = __int_as_float(wmb);
            u64 mask = __ballot(bv == wmax);
            int fl = __ffsll((long long)mask) - 1;             // lowest lane => lowest p
            int fj = __builtin_amdgcn_readlane(bj, fl);
            int p = (wid << 10) + (fl << 4) + fj;
            if (lane == 0) s_red[par][wid] = ((u64)(u32)wmb << 32) | (u32)(4095 - p);
            // barrier WITHOUT vmcnt(0): only LDS must be visible (s_red); the cents
            // global store stays in flight. Parity double-buffer makes 1-step skew safe.
            asm volatile("s_waitcnt lgkmcnt(0)\n\ts_barrier" ::: "memory");
            u64 m0 = umax64(s_red[par][0], s_red[par][1]);
            u64 m1 = umax64(s_red[par][2], s_red[par][3]);
            u64 m  = umax64(m0, m1);
            far = 4095 - (int)(m & 0xFFFu);
            par ^= 1;
        }
    } else {
        // ---------------- workers: 112 blocks = 448 waves ----------------
        const int w = (blockIdx.x - 16)*4 + wid;   // 0..447
        const int quad = lane >> 4;
        const int col = lane & 15;
        frag_ab Bf[4][2];
#pragma unroll
        for (int nt = 0; nt < 4; nt++)
#pragma unroll
            for (int kh = 0; kh < 2; kh++){
                const float* wr = w0 + (nt*16 + col)*67 + 3 + kh*32 + quad*8;
#pragma unroll
                for (int j = 0; j < 8; j++) Bf[nt][kh][j] = (short)f2bf(wr[j]);
            }
        float wx[4], wy[4], wz[4], biasl[4];
#pragma unroll
        for (int nt = 0; nt < 4; nt++){
            const float* wb = w0 + (nt*16 + col)*67;
            wx[nt] = wb[0]; wy[nt] = wb[1]; wz[nt] = wb[2];
            biasl[nt] = bias0[nt*16 + col];
        }
        float ssum[4] = {0,0,0,0}, ssq[4] = {0,0,0,0};
        u16* xo = (u16*)x1buf;
        const float RAD2 = (float)(0.9*0.9);
        const int b = w & 15;                       // 28 waves per batch
        const float* gx = xyz + (size_t)b*NN*3;
        for (int s = (w >> 4); s < NPOINT; s += 28){
            const int g = (b << 10) + s;
            int ci;
            while ((ci = __hip_atomic_load(&cents[g], __ATOMIC_RELAXED, __HIP_MEMORY_SCOPE_AGENT)) == -1)
                __builtin_amdgcn_s_sleep(32);
            const float* cp = xyz + ((size_t)b*NN + ci)*3;
            float cx = cp[0], cy = cp[1], cz = cp[2];
            if (lane < 3) out[g*3 + lane] = cp[lane];   // new_xyz output
            // ---- ball query (verbatim math) ----
            float sc = __fadd_rn(__fadd_rn(__fmul_rn(cx,cx), __fmul_rn(cy,cy)), __fmul_rn(cz,cz));
            int* gout = gidx + (size_t)g*NSAMPLE;
            int found = 0; int first = -1;
            for (int base = 0; base < NN; base += 64){
                int i = base + lane;
                float pxv = gx[i*3+0], pyv = gx[i*3+1], pzv = gx[i*3+2];
                float sp = __fadd_rn(__fadd_rn(__fmul_rn(pxv,pxv), __fmul_rn(pyv,pyv)), __fmul_rn(pzv,pzv));
                float dot = __fadd_rn(__fadd_rn(__fmul_rn(cx,pxv), __fmul_rn(cy,pyv)), __fmul_rn(cz,pzv));
                float d2 = __fsub_rn(__fadd_rn(sc, sp), __fmul_rn(2.0f, dot));
                float dd = __fsqrt_rn(fmaxf(d2, 0.0f));
                bool in = !(dd > RAD2);
                u64 m = __ballot(in);
                int cnt = __popcll(m);
                if (in){
                    int slot = found + __popcll(m & ((1ull<<lane) - 1ull));
                    if (slot < NSAMPLE) gout[slot] = i;
                }
                if (found == 0 && cnt > 0) first = base + (__ffsll(m) - 1);
                found += cnt;
                if (found >= NSAMPLE) break;
            }
            if (found < NSAMPLE){
                if (found == 0) first = ci;
                for (int slot = found + lane; slot < NSAMPLE; slot += 64) gout[slot] = first;
            }
            // own-wave gidx stores -> own-wave loads: drain own VMEM only (no agent fence)
            asm volatile("s_waitcnt vmcnt(0)" ::: "memory");
            // ---- conv1 for this centroid's 32 rows (2 MFMA tiles); fp32 points gathered ----
#pragma unroll
            for (int t = 0; t < 2; t++){
                const int m0 = g*32 + t*16;
                const int gg = gidx[m0 + col];
                const float* prow = points + ((size_t)(b<<12) + gg)*64;
                float4 f0a = *(const float4*)(prow + quad*8);
                float4 f0b = *(const float4*)(prow + quad*8 + 4);
                float4 f1a = *(const float4*)(prow + 32 + quad*8);
                float4 f1b = *(const float4*)(prow + 32 + quad*8 + 4);
                frag_ab Af0, Af1;
                {
                    const float* fa = (const float*)&f0a;
                    const float* fb = (const float*)&f0b;
#pragma unroll
                    for (int j = 0; j < 4; j++){ Af0[j] = (short)f2bf(fa[j]); Af0[4+j] = (short)f2bf(fb[j]); }
                    const float* fc = (const float*)&f1a;
                    const float* fd = (const float*)&f1b;
#pragma unroll
                    for (int j = 0; j < 4; j++){ Af1[j] = (short)f2bf(fc[j]); Af1[4+j] = (short)f2bf(fd[j]); }
                }
                frag_cd acc[4];
#pragma unroll
                for (int nt = 0; nt < 4; nt++){
                    acc[nt] = (frag_cd){0.f, 0.f, 0.f, 0.f};
                    acc[nt] = __builtin_amdgcn_mfma_f32_16x16x32_bf16(Af0, Bf[nt][0], acc[nt], 0, 0, 0);
                    acc[nt] = __builtin_amdgcn_mfma_f32_16x16x32_bf16(Af1, Bf[nt][1], acc[nt], 0, 0, 0);
                }
#pragma unroll
                for (int r = 0; r < 4; r++){
                    const int rowm = m0 + quad*4 + r;
                    const int pt = gidx[rowm];
                    const float* p3 = xyz + ((size_t)(b<<12) + pt)*3;
                    float xnx = p3[0]-cx, xny = p3[1]-cy, xnz = p3[2]-cz;
#pragma unroll
                    for (int nt = 0; nt < 4; nt++){
                        float v = acc[nt][r] + biasl[nt];
                        v = fmaf(wx[nt], xnx, v);
                        v = fmaf(wy[nt], xny, v);
                        v = fmaf(wz[nt], xnz, v);
                        xo[(size_t)rowm*64 + nt*16 + col] = f2bf(v);
                        ssum[nt] += v;
                        ssq[nt] = fmaf(v, v, ssq[nt]);
                    }
                }
            }
        }
        // stats reduce (lanes sharing col) + global atomics (device-scope, coherent)
#pragma unroll
        for (int nt = 0; nt < 4; nt++){
            ssum[nt] += __shfl_xor(ssum[nt], 16); ssq[nt] += __shfl_xor(ssq[nt], 16);
            ssum[nt] += __shfl_xor(ssum[nt], 32); ssq[nt] += __shfl_xor(ssq[nt], 32);
        }
        if (quad == 0){
            float* st = stats + (blockIdx.x & 7)*256;
#pragma unroll
            for (int nt = 0; nt < 4; nt++){
                atomicAdd(&st[nt*16 + col], ssum[nt]);
                atomicAdd(&st[128 + nt*16 + col], ssq[nt]);
            }
        }
    }
}

// ---- in-block BN finalize: stats (8 replicas) + g/beta -> saff[a:0..127 | b:128..255] ----
__device__ inline void block_finalize(const float* __restrict__ stats, const float* __restrict__ g,
                                      const float* __restrict__ beta, float* saff, int C, int tid)
{
    if (tid < C){
        float sm = 0.f, sq = 0.f;
#pragma unroll
        for (int r = 0; r < 8; r++){ sm += stats[r*256+tid]; sq += stats[r*256+128+tid]; }
        const float invM = 1.0f / 524288.0f;
        float mu  = sm * invM;
        float var = fmaxf(sq * invM - mu*mu, 0.0f);
        float inv = 1.0f / sqrtf(var + 1e-5f);
        float a = g[tid] * inv;
        saff[tid] = a;
        saff[128+tid] = beta[tid] - mu*a;
    }
}

// ---- unpack 8 packed-bf16, apply affine+relu, emit bf16 frag half ----
__device__ inline void unpack_affine_relu(uint4 u, const float* ak, const float* bk, short* dst){
    const u32* uu = (const u32*)&u;
#pragma unroll
    for (int q = 0; q < 4; q++){
        u32 v = uu[q];
        float x0 = bf2f(v & 0xffffu);
        float x1 = bf2f(v >> 16);
        float f0 = fmaxf(fmaf(ak[2*q],   x0, bk[2*q]),   0.f);
        float f1 = fmaxf(fmaf(ak[2*q+1], x1, bk[2*q+1]), 0.f);
        dst[2*q]   = (short)f2bf(f0);
        dst[2*q+1] = (short)f2bf(f1);
    }
}

// ---------------- conv2 (MFMA): 64->64, in-block BN0 finalize, BN+relu on load, fused stats ----------------
__global__ __launch_bounds__(256) void conv2_kernel(const u32* __restrict__ xin, const float* __restrict__ stats_in,
                                                    const float* __restrict__ gw, const float* __restrict__ beta,
                                                    const float* __restrict__ w, const float* __restrict__ bias,
                                                    u32* __restrict__ xout, float* __restrict__ stats)
{
    __shared__ float saff[256];
    const int tid = threadIdx.x;
    block_finalize(stats_in, gw, beta, saff, 64, tid);
    const int lane = tid & 63;
    const int wid = tid >> 6;
    const int quad = lane >> 4;
    const int col = lane & 15;
    frag_ab Bf[4][2];
#pragma unroll
    for (int nt = 0; nt < 4; nt++)
#pragma unroll
        for (int kh = 0; kh < 2; kh++){
            const float* wr = w + (nt*16 + col)*64 + kh*32 + quad*8;
#pragma unroll
            for (int j = 0; j < 8; j++) Bf[nt][kh][j] = (short)f2bf(wr[j]);
        }
    float biasl[4];
#pragma unroll
    for (int nt = 0; nt < 4; nt++) biasl[nt] = bias[nt*16 + col];
    __syncthreads();
    float ak[2][8], bk[2][8];
#pragma unroll
    for (int kh = 0; kh < 2; kh++)
#pragma unroll
        for (int j = 0; j < 8; j++){
            int k = kh*32 + quad*8 + j;
            ak[kh][j] = saff[k]; bk[kh][j] = saff[128+k];
        }
    float ssum[4] = {0,0,0,0}, ssq[4] = {0,0,0,0};
    u16* xo = (u16*)xout;
    const int tile0 = blockIdx.x*64 + wid*16;
    for (int t = 0; t < 16; t++){
        const size_t m0 = (size_t)(tile0 + t) * 16;
        const u32* arow = xin + (m0 + col)*32;
        uint4 u0 = *(const uint4*)(arow + quad*4);
        uint4 u1 = *(const uint4*)(arow + 16 + quad*4);
        frag_ab Af0, Af1;
        unpack_affine_relu(u0, ak[0], bk[0], (short*)&Af0);
        unpack_affine_relu(u1, ak[1], bk[1], (short*)&Af1);
        frag_cd acc[4];
#pragma unroll
        for (int nt = 0; nt < 4; nt++){
            acc[nt] = (frag_cd){biasl[nt], biasl[nt], biasl[nt], biasl[nt]};
            acc[nt] = __builtin_amdgcn_mfma_f32_16x16x32_bf16(Af0, Bf[nt][0], acc[nt], 0, 0, 0);
            acc[nt] = __builtin_amdgcn_mfma_f32_16x16x32_bf16(Af1, Bf[nt][1], acc[nt], 0, 0, 0);
        }
#pragma unroll
        for (int nt = 0; nt < 4; nt++){
#pragma unroll
            for (int r = 0; r < 4; r++){
                float v = acc[nt][r];
                xo[(m0 + quad*4 + r)*64 + nt*16 + col] = f2bf(v);
                ssum[nt] += v;
                ssq[nt] = fmaf(v, v, ssq[nt]);
            }
        }
    }
#pragma unroll
    for (int nt = 0; nt < 4; nt++){
        ssum[nt] += __shfl_xor(ssum[nt], 16); ssq[nt] += __shfl_xor(ssq[nt], 16);
        ssum[nt] += __shfl_xor(ssum[nt], 32); ssq[nt] += __shfl_xor(ssq[nt], 32);
    }
    if (quad == 0){
        float* st = stats + (blockIdx.x & 7)*256;
#pragma unroll
        for (int nt = 0; nt < 4; nt++){
            atomicAdd(&st[nt*16 + col], ssum[nt]);
            atomicAdd(&st[128 + nt*16 + col], ssq[nt]);
        }
    }
}

// ---------------- conv3 (MFMA): 64->128, in-block BN1 finalize, fused stats + group max/min ----------------
__global__ __launch_bounds__(256) void conv3_kernel(const u32* __restrict__ xin, const float* __restrict__ stats_in,
                                                    const float* __restrict__ gw, const float* __restrict__ beta,
                                                    const float* __restrict__ w, const float* __restrict__ bias,
                                                    float* __restrict__ gmax, float* __restrict__ gmin,
                                                    float* __restrict__ stats)
{
    __shared__ float saff[256];
    const int tid = threadIdx.x;
    block_finalize(stats_in, gw, beta, saff, 64, tid);
    const int lane = tid & 63;
    const int wid = tid >> 6;
    const int quad = lane >> 4;
    const int col = lane & 15;
    frag_ab Bf[8][2];
#pragma unroll
    for (int nt = 0; nt < 8; nt++)
#pragma unroll
        for (int kh = 0; kh < 2; kh++){
            const float* wr = w + (nt*16 + col)*64 + kh*32 + quad*8;
#pragma unroll
            for (int j = 0; j < 8; j++) Bf[nt][kh][j] = (short)f2bf(wr[j]);
        }
    float biasl[8];
#pragma unroll
    for (int nt = 0; nt < 8; nt++) biasl[nt] = bias[nt*16 + col];
    __syncthreads();
    float ak[2][8], bk[2][8];
#pragma unroll
    for (int kh = 0; kh < 2; kh++)
#pragma unroll
        for (int j = 0; j < 8; j++){
            int k = kh*32 + quad*8 + j;
            ak[kh][j] = saff[k]; bk[kh][j] = saff[128+k];
        }
    float ssum[8], ssq[8], mx[8], mn[8];
#pragma unroll
    for (int nt = 0; nt < 8; nt++){ ssum[nt] = 0.f; ssq[nt] = 0.f; }
    const int tile0 = blockIdx.x*32 + wid*8;
#pragma unroll 2
    for (int t = 0; t < 8; t++){
        const size_t m0 = (size_t)(tile0 + t) * 16;
        const u32* arow = xin + (m0 + col)*32;
        uint4 u0 = *(const uint4*)(arow + quad*4);
        uint4 u1 = *(const uint4*)(arow + 16 + quad*4);
        frag_ab Af0, Af1;
        unpack_affine_relu(u0, ak[0], bk[0], (short*)&Af0);
        unpack_affine_relu(u1, ak[1], bk[1], (short*)&Af1);
        frag_cd acc[8];
#pragma unroll
        for (int nt = 0; nt < 8; nt++){
            acc[nt] = (frag_cd){biasl[nt], biasl[nt], biasl[nt], biasl[nt]};
            acc[nt] = __builtin_amdgcn_mfma_f32_16x16x32_bf16(Af0, Bf[nt][0], acc[nt], 0, 0, 0);
            acc[nt] = __builtin_amdgcn_mfma_f32_16x16x32_bf16(Af1, Bf[nt][1], acc[nt], 0, 0, 0);
        }
#pragma unroll
        for (int nt = 0; nt < 8; nt++){
            float a0 = fmaxf(fmaxf(acc[nt][0], acc[nt][1]), fmaxf(acc[nt][2], acc[nt][3]));
            float n0 = fminf(fminf(acc[nt][0], acc[nt][1]), fminf(acc[nt][2], acc[nt][3]));
            if ((t & 1) == 0){ mx[nt] = a0; mn[nt] = n0; }
            else { mx[nt] = fmaxf(mx[nt], a0); mn[nt] = fminf(mn[nt], n0); }
#pragma unroll
            for (int r = 0; r < 4; r++){
                float v = acc[nt][r];
                ssum[nt] += v;
                ssq[nt] = fmaf(v, v, ssq[nt]);
            }
        }
        if (t & 1){
#pragma unroll
            for (int nt = 0; nt < 8; nt++){
                mx[nt] = fmaxf(mx[nt], __shfl_xor(mx[nt], 16));
                mn[nt] = fminf(mn[nt], __shfl_xor(mn[nt], 16));
                mx[nt] = fmaxf(mx[nt], __shfl_xor(mx[nt], 32));
                mn[nt] = fminf(mn[nt], __shfl_xor(mn[nt], 32));
            }
            if (quad == 0){
                const int g = (tile0 + t - 1) >> 1;
#pragma unroll
                for (int nt = 0; nt < 8; nt++){
                    gmax[(size_t)g*128 + nt*16 + col] = mx[nt];
                    gmin[(size_t)g*128 + nt*16 + col] = mn[nt];
                }
            }
        }
    }
#pragma unroll
    for (int nt = 0; nt < 8; nt++){
        ssum[nt] += __shfl_xor(ssum[nt], 16); ssq[nt] += __shfl_xor(ssq[nt], 16);
        ssum[nt] += __shfl_xor(ssum[nt], 32); ssq[nt] += __shfl_xor(ssq[nt], 32);
    }
    if (quad == 0){
        float* st = stats + (blockIdx.x & 7)*256;
#pragma unroll
        for (int nt = 0; nt < 8; nt++){
            atomicAdd(&st[nt*16 + col], ssum[nt]);
            atomicAdd(&st[128 + nt*16 + col], ssq[nt]);
        }
    }
}

// ---------------- pool: in-block BN2 finalize + relu from group max/min ----------------
__global__ __launch_bounds__(256) void pool_kernel(const float* __restrict__ gmax, const float* __restrict__ gmin,
                                                   const float* __restrict__ stats_in, const float* __restrict__ gw,
                                                   const float* __restrict__ beta, float* __restrict__ out)
{
    __shared__ float saff[256];
    const int tid = threadIdx.x;
    block_finalize(stats_in, gw, beta, saff, 128, tid);
    __syncthreads();
    const int base = blockIdx.x*2048 + tid;
#pragma unroll
    for (int k = 0; k < 8; k++){
        int idx = base + k*256;
        int o = idx & 127;
        float a = saff[o], bsh = saff[128+o];
        float v = (a >= 0.f) ? fmaf(a, gmax[idx], bsh) : fmaf(a, gmin[idx], bsh);
        out[(size_t)BB*NPOINT*3 + idx] = fmaxf(v, 0.f);
    }
}

extern "C" void kernel_launch(void* const* d_in, const int* in_sizes, int n_in,
                              void* d_out, int out_size, void* d_ws, size_t ws_size,
                              hipStream_t stream)
{
    const float* xyz    = (const float*)d_in[0];
    const float* points = (const float*)d_in[1];
    const float* w0  = (const float*)d_in[2];
    const float* b0  = (const float*)d_in[3];
    const float* g0  = (const float*)d_in[4];
    const float* be0 = (const float*)d_in[5];
    const float* w1  = (const float*)d_in[6];
    const float* b1  = (const float*)d_in[7];
    const float* g1  = (const float*)d_in[8];
    const float* be1 = (const float*)d_in[9];
    const float* w2  = (const float*)d_in[10];
    const float* b2  = (const float*)d_in[11];
    const float* g2  = (const float*)d_in[12];
    const float* be2 = (const float*)d_in[13];
    float* out = (float*)d_out;
    char* ws = (char*)d_ws;

    int*   cents = (int*)(ws + 0);                 //  64 KiB (memset 0xFF = -1 sentinel)
    int*   gidx  = (int*)(ws + 262144);            //   2 MiB -> ends 2359296
    float* stats = (float*)(ws + 2359296);         //  24 KiB (3 layers x 8 replicas x 256 f)
    u32*   x1buf = (u32*)(ws + 2386944);           //  64 MiB (conv1 out bf16)
    u32*   x2buf = (u32*)(ws + 69495808);          //  64 MiB (conv2 out bf16)
    float* gmax  = (float*)(ws + 136604672);       // 8.4 MiB (conv3 out)
    float* gmin  = (float*)(ws + 144993280);       // 8.4 MiB

    hipMemsetAsync(cents, 0xFF, NPOINT*BB*sizeof(int), stream);   // -1 sentinels
    hipMemsetAsync(stats, 0, 6144*sizeof(float), stream);
    mega_kernel<<<128, 256, 0, stream>>>(xyz, points, w0, b0, cents, gidx, out, stats, x1buf);
    conv2_kernel<<<512, 256, 0, stream>>>(x1buf, stats, g0, be0, w1, b1, x2buf, stats + 2048);
    conv3_kernel<<<1024, 256, 0, stream>>>(x2buf, stats + 2048, g1, be1, w2, b2, gmax, gmin, stats + 4096);
    pool_kernel<<<1024, 256, 0, stream>>>(gmax, gmin, stats + 4096, g2, be2, out);
}